// Round 1
// baseline (273.513 us; speedup 1.0000x reference)
//
#include <hip/hip_runtime.h>
#include <math.h>

// Problem constants
#define BATCH 256
#define IC    1152
#define EDIM  8
#define NC    10
#define DV    16

// Tiling
#define ITILE 8                   // i's per block
#define NB    32                  // b's per block (looped)
#define NTHREADS 256              // 8 i * 2 c-halves * 16 d
#define ICHUNKS (IC / ITILE)      // 144
#define BCHUNKS (BATCH / NB)      // 8
#define SCD (NC * DV)             // 160
#define SPART_STRIDE (BATCH * SCD) // 40960 floats per i-chunk slab

// ---------------------------------------------------------------------------
// Main fused kernel. Thread (il, ch, d): il = i within tile (0..7),
// ch = c-half (0..1, covering c = ch*5 .. ch*5+4), d = dim_vec index (0..15).
// tid = il*32 + ch*16 + d  → d = bits 0..3, ch = bit 4, il = bits 5..7.
// Each thread holds W[i, c_k, d, 0:8] for its 5 c's in registers (40 VGPRs),
// loops over 32 batch elements, recomputing u_hat[b,i,c_k,d] per b.
//
// MODE 1: c = softmax(bias)         -> accumulate s1 partials
// MODE 2: agr1 = u_hat . v1; b2 = agr1 + 2*bias (written to ws);
//         c2 = softmax(b2)          -> accumulate s2 partials
// MODE 3: agr2 = u_hat . v2; b3 = agr2 + b2 + bias;
//         c3 = softmax(b3)          -> accumulate s3 partials
// ---------------------------------------------------------------------------
template<int MODE>
__global__ __launch_bounds__(NTHREADS)
void caps_main(const float* __restrict__ x,
               const float* __restrict__ W,
               const float* __restrict__ bias,
               const float* __restrict__ v_in,
               float* __restrict__ b2,
               float* __restrict__ s_part)
{
    __shared__ float sx[NB][ITILE * EDIM];   // 8 KB: x[b-chunk][i-tile][e]
    __shared__ float sv[NB][SCD];            // 20 KB: v[b-chunk][c][d] (MODE 2,3)
    __shared__ float sred[4][2][DV][5];      // 2.5 KB: cross-wave i-reduction

    const int tid = threadIdx.x;
    const int d   = tid & 15;
    const int ch  = (tid >> 4) & 1;
    const int il  = tid >> 5;                // 0..7
    const int icb = blockIdx.x;              // 0..143
    const int bcb = blockIdx.y;              // 0..7
    const int i0  = icb * ITILE;
    const int b0  = bcb * NB;
    const int i   = i0 + il;

    // ---- stage x slice into LDS (coalesced float4) ----
    {
        const float4* xg = (const float4*)x;
        float4* xs = (float4*)&sx[0][0];
        #pragma unroll
        for (int f = tid; f < NB * ITILE * EDIM / 4; f += NTHREADS) {
            int bb = f >> 4;        // 16 float4 = one (b, i-tile) row
            int w  = f & 15;
            xs[f] = xg[(size_t)(b0 + bb) * (IC * EDIM / 4) + i0 * (EDIM / 4) + w];
        }
    }
    if (MODE != 1) {
        const float4* vg = (const float4*)v_in;
        float4* vs = (float4*)&sv[0][0];
        #pragma unroll
        for (int f = tid; f < NB * SCD / 4; f += NTHREADS) {
            int bb = f / (SCD / 4);
            int w  = f % (SCD / 4);
            vs[f] = vg[(size_t)(b0 + bb) * (SCD / 4) + w];
        }
    }

    // ---- load W fragment + bias into registers ----
    float4 w4[5][2];
    float  bv[5];
    const float4* Wg = (const float4*)W;
    #pragma unroll
    for (int k = 0; k < 5; ++k) {
        int c = ch * 5 + k;
        size_t base = ((size_t)(i * NC + c) * DV + d) * 2;  // float4 units
        w4[k][0] = Wg[base];
        w4[k][1] = Wg[base + 1];
        bv[k]    = bias[i * NC + c];
    }

    float cw[5];
    if (MODE == 1) {
        // softmax(bias[i,:]) — batch-independent, compute once
        float mx = fmaxf(fmaxf(fmaxf(bv[0], bv[1]), fmaxf(bv[2], bv[3])), bv[4]);
        mx = fmaxf(mx, __shfl_xor(mx, 16));
        float ssum = 0.f, ex[5];
        #pragma unroll
        for (int k = 0; k < 5; ++k) { ex[k] = __expf(bv[k] - mx); ssum += ex[k]; }
        ssum += __shfl_xor(ssum, 16);
        float inv = 1.0f / ssum;
        #pragma unroll
        for (int k = 0; k < 5; ++k) cw[k] = ex[k] * inv;
    }

    __syncthreads();

    for (int bb = 0; bb < NB; ++bb) {
        const int b = b0 + bb;
        const float4 x0 = ((const float4*)&sx[bb][il * EDIM])[0];
        const float4 x1 = ((const float4*)&sx[bb][il * EDIM])[1];

        // u_hat[b, i, c_k, d] = W[i,c_k,d,:] . x[b,i,:]
        float u[5];
        #pragma unroll
        for (int k = 0; k < 5; ++k) {
            float acc = w4[k][0].x * x0.x;
            acc = fmaf(w4[k][0].y, x0.y, acc);
            acc = fmaf(w4[k][0].z, x0.z, acc);
            acc = fmaf(w4[k][0].w, x0.w, acc);
            acc = fmaf(w4[k][1].x, x1.x, acc);
            acc = fmaf(w4[k][1].y, x1.y, acc);
            acc = fmaf(w4[k][1].z, x1.z, acc);
            acc = fmaf(w4[k][1].w, x1.w, acc);
            u[k] = acc;
        }

        if (MODE != 1) {
            // agreement: reduce u*v over the 16 d-lanes
            float t[5];
            #pragma unroll
            for (int k = 0; k < 5; ++k)
                t[k] = u[k] * sv[bb][(ch * 5 + k) * DV + d];
            #pragma unroll
            for (int k = 0; k < 5; ++k) {
                t[k] += __shfl_xor(t[k], 1);
                t[k] += __shfl_xor(t[k], 2);
                t[k] += __shfl_xor(t[k], 4);
                t[k] += __shfl_xor(t[k], 8);
            }
            float br[5];
            if (MODE == 2) {
                #pragma unroll
                for (int k = 0; k < 5; ++k) br[k] = t[k] + 2.0f * bv[k];
                if (d == 0) {
                    #pragma unroll
                    for (int k = 0; k < 5; ++k)
                        b2[((size_t)b * IC + i) * NC + ch * 5 + k] = br[k];
                }
            } else {
                #pragma unroll
                for (int k = 0; k < 5; ++k)
                    br[k] = t[k] + b2[((size_t)b * IC + i) * NC + ch * 5 + k] + bv[k];
            }
            // softmax over the 10 c's (5 local + partner half via xor-16)
            float mx = fmaxf(fmaxf(fmaxf(br[0], br[1]), fmaxf(br[2], br[3])), br[4]);
            mx = fmaxf(mx, __shfl_xor(mx, 16));
            float ssum = 0.f, ex[5];
            #pragma unroll
            for (int k = 0; k < 5; ++k) { ex[k] = __expf(br[k] - mx); ssum += ex[k]; }
            ssum += __shfl_xor(ssum, 16);
            float inv = 1.0f / ssum;
            #pragma unroll
            for (int k = 0; k < 5; ++k) cw[k] = ex[k] * inv;
        }

        // s contribution: cw * u_hat, reduced over the block's 8 i's
        float sval[5];
        #pragma unroll
        for (int k = 0; k < 5; ++k) sval[k] = cw[k] * u[k];
        #pragma unroll
        for (int k = 0; k < 5; ++k) sval[k] += __shfl_xor(sval[k], 32); // i-pair in wave
        if ((tid & 32) == 0) {
            int w = tid >> 6;
            #pragma unroll
            for (int k = 0; k < 5; ++k) sred[w][ch][d][k] = sval[k];
        }
        __syncthreads();
        if (tid < SCD) {
            int c  = tid >> 4;
            int dd = tid & 15;
            int kk = c % 5, cc = c / 5;
            float s = (sred[0][cc][dd][kk] + sred[1][cc][dd][kk])
                    + (sred[2][cc][dd][kk] + sred[3][cc][dd][kk]);
            s_part[((size_t)icb * BATCH + b) * SCD + tid] = s;
        }
        __syncthreads();
    }
}

// ---------------------------------------------------------------------------
// Reduce s-partials over the 144 i-chunks and apply squash.
// Block = 16 (b,c) groups x 16 d. Grid = 2560/16 = 160 blocks.
// ---------------------------------------------------------------------------
__global__ __launch_bounds__(256)
void caps_squash(const float* __restrict__ s_part, float* __restrict__ out)
{
    const int tid = threadIdx.x;
    const int bc  = blockIdx.x * 16 + (tid >> 4);
    const int d   = tid & 15;
    const size_t off = (size_t)bc * DV + d;

    float a0 = 0.f, a1 = 0.f, a2 = 0.f, a3 = 0.f;
    #pragma unroll 4
    for (int ic = 0; ic < ICHUNKS; ic += 4) {
        a0 += s_part[(size_t)(ic + 0) * SPART_STRIDE + off];
        a1 += s_part[(size_t)(ic + 1) * SPART_STRIDE + off];
        a2 += s_part[(size_t)(ic + 2) * SPART_STRIDE + off];
        a3 += s_part[(size_t)(ic + 3) * SPART_STRIDE + off];
    }
    float s = (a0 + a1) + (a2 + a3);

    float sq = s * s;
    sq += __shfl_xor(sq, 1);
    sq += __shfl_xor(sq, 2);
    sq += __shfl_xor(sq, 4);
    sq += __shfl_xor(sq, 8);

    // scale = sq/(1+sq)/sqrt(sq+EPS), EPS = 1e-7 (matches reference)
    float scale = sq / ((1.0f + sq) * sqrtf(sq + 1e-7f));
    out[off] = scale * s;
}

// ---------------------------------------------------------------------------
extern "C" void kernel_launch(void* const* d_in, const int* in_sizes, int n_in,
                              void* d_out, int out_size, void* d_ws, size_t ws_size,
                              hipStream_t stream)
{
    const float* x    = (const float*)d_in[0];   // [256,1152,8]
    const float* W    = (const float*)d_in[1];   // [1152,10,16,8]
    const float* bias = (const float*)d_in[2];   // [1152,10]
    float* out = (float*)d_out;                  // [256,10,16]

    float* ws     = (float*)d_ws;
    float* s_part = ws;                                        // 144*40960 = 5,898,240 f
    float* v      = s_part + (size_t)ICHUNKS * SPART_STRIDE;   // 40,960 f
    float* b2     = v + SPART_STRIDE;                          // 2,949,120 f
    // total ws use: ~35.6 MB

    dim3 grid(ICHUNKS, BCHUNKS);  // 144 x 8 = 1152 blocks

    // iter 1
    caps_main<1><<<grid, NTHREADS, 0, stream>>>(x, W, bias, v, b2, s_part);
    caps_squash<<<160, 256, 0, stream>>>(s_part, v);
    // iter 2
    caps_main<2><<<grid, NTHREADS, 0, stream>>>(x, W, bias, v, b2, s_part);
    caps_squash<<<160, 256, 0, stream>>>(s_part, v);
    // final
    caps_main<3><<<grid, NTHREADS, 0, stream>>>(x, W, bias, v, b2, s_part);
    caps_squash<<<160, 256, 0, stream>>>(s_part, out);
}